// Round 3
// baseline (5765.707 us; speedup 1.0000x reference)
//
#include <hip/hip_runtime.h>
#include <stdint.h>

#define T_STEPS 512
#define RING 16

typedef short short8 __attribute__((ext_vector_type(8)));
typedef float f32x16 __attribute__((ext_vector_type(16)));

// ---- ws layout (bytes) ----
// hdr: [0..7] per-group XCD mask, [16] arrive1, [17] arrive2,
//      [32..39] selftest counters, [48..55] group fail flags
#define OFF_HDR 0
#define OFF_DONE 256                        // [rg][t][8 counters x 64B] = 2 MB
#define DONE_BYTES (8 * 512 * 8 * 64)
#define OFF_RING (OFF_DONE + DONE_BYTES)    // [slot 16][rg 8][64 cells x 256B] = 2 MB
#define SLOT_BYTES (8 * 16384)
#define RING_BYTES (RING * SLOT_BYTES)
#define OFF_XF (OFF_RING + RING_BYTES)      // [rg][t][kx 32][256B] = 32 MB
#define XF_BYTES (8 * 512 * 32 * 256)
#define OFF_WP (OFF_XF + XF_BYTES)          // [ct 128][kt 96][lane 64][16B] = 12.58 MB
#define WP_BYTES (128 * 96 * 64 * 16)
#define MEMSET_BYTES (OFF_RING + SLOT_BYTES)  // hdr + done + ring slot 0

__device__ __forceinline__ unsigned short f2bf(float f) {
  unsigned u = __float_as_uint(f);
  u += 0x7fffu + ((u >> 16) & 1u);   // RNE
  return (unsigned short)(u >> 16);
}

// ---- prep: x [B][T][D] f32 -> xf A-frag cells ----
// cell(rg,t,kx) 256B = [m 8][kseg 2][8] bf16 ; element = x[rg*8+m][t][kx*16+kseg*8+j]
__global__ __launch_bounds__(256) void k_xpack(const float* __restrict__ x,
                                               unsigned short* __restrict__ xf) {
  int o = blockIdx.x * 256 + threadIdx.x;       // 2,097,152 16B lines
  int kseg = o & 1;
  int m = (o >> 1) & 7;
  int kx = (o >> 4) & 31;
  int t = (o >> 9) & 511;
  int rg = (o >> 18) & 7;
  const float* src = x + ((size_t)(rg * 8 + m) * 512 + t) * 512 + kx * 16 + kseg * 8;
  float4 v0 = *(const float4*)src;
  float4 v1 = *(const float4*)(src + 4);
  short8 wv;
  wv[0] = (short)f2bf(v0.x); wv[1] = (short)f2bf(v0.y);
  wv[2] = (short)f2bf(v0.z); wv[3] = (short)f2bf(v0.w);
  wv[4] = (short)f2bf(v1.x); wv[5] = (short)f2bf(v1.y);
  wv[6] = (short)f2bf(v1.z); wv[7] = (short)f2bf(v1.w);
  *(short8*)(xf + (size_t)o * 8) = wv;
}

// ---- prep: Wx/Wh -> B-frags wp[ct][kt][lane] ----
// lane l: col cp = ct*32 + (l&31), k = kt*16 + (l>>5)*8 + j
// cp = (u>>3)*32 + gate*8 + (u&7)  ->  orig col = gate*1024 + ct*8 + (cp&7)
__global__ __launch_bounds__(256) void k_wpack(const float* __restrict__ Wx,
                                               const float* __restrict__ Wh,
                                               unsigned short* __restrict__ wp) {
  __shared__ float tile[128][32];
  int tid = threadIdx.x;
  int ch = blockIdx.x;     // 0..11 : K chunk of 128 rows
  int ct = blockIdx.y;     // 0..127 : 32-col tile
  int c = tid & 31, kl8 = tid >> 5;
  int gate = c >> 3;
  int co = gate * 1024 + ct * 8 + (c & 7);
  const float* src;
  int K0;
  if (ch < 4) { src = Wx; K0 = ch * 128; }
  else        { src = Wh; K0 = ch * 128 - 512; }
#pragma unroll
  for (int p = 0; p < 16; ++p) {
    int row = p * 8 + kl8;
    tile[row][c] = src[(size_t)(K0 + row) * 4096 + co];
  }
  __syncthreads();
#pragma unroll
  for (int h2 = 0; h2 < 2; ++h2) {
    int line = h2 * 256 + tid;
    int kt2 = line >> 6, l = line & 63;
    short8 v;
#pragma unroll
    for (int j = 0; j < 8; ++j)
      v[j] = (short)f2bf(tile[kt2 * 16 + (l >> 5) * 8 + j][l & 31]);
    *(short8*)(wp + ((size_t)(ct * 96 + ch * 8 + kt2) * 64 + l) * 8) = v;
  }
}

// ---- persistent scan: 8 independent 8-row recurrences ----
// group rg = bid&7 (rows rg*8..+8), member cm = bid>>3 (units cm*32..+32).
// wave w owns 32 packed cols (units cm*32+w*8..+8), FULL K=1536 per wave:
// no intra-block barrier in the loop. Wh B-frags in 256 VGPRs, Wx B-frags in LDS.
// Static LDS = exactly 128 KiB (131072 B): R1/R2 used 131076 B, 4 B past the
// largest HIP-source-verified workgroup LDS -> suspected silent launch failure
// (absmax identical to all-zero output). Consensus broadcast moved to global hdr.
// Communication: XCD-local L2 (plain stores + sc0 loads + L2 atomics) when the
// group is XCD-uniform (runtime-verified); agent-scope (LLC) fallback otherwise.
#define H_LDF(BUF, BASE)                                                         \
  _Pragma("unroll") for (int j = 0; j < 8; ++j)                                  \
      asm volatile("global_load_dwordx4 %0, %1, off sc0"                         \
                   : "=v"(BUF[j]) : "v"(hb + (BASE + j) * 128));
#define H_LDA(BUF, BASE)                                                         \
  _Pragma("unroll") for (int j = 0; j < 8; ++j)                                  \
      asm volatile("global_load_dwordx4 %0, %1, off sc0 sc1"                     \
                   : "=v"(BUF[j]) : "v"(hb + (BASE + j) * 128));
#define H_WAIT8 { asm volatile("s_waitcnt vmcnt(8)" ::: "memory");               \
                  __builtin_amdgcn_sched_barrier(0); }
#define H_WAIT0 { asm volatile("s_waitcnt vmcnt(0)" ::: "memory");               \
                  __builtin_amdgcn_sched_barrier(0); }
#define H_MM(BUF, BASE)                                                          \
  _Pragma("unroll") for (int j = 0; j < 8; ++j)                                  \
      acc = __builtin_amdgcn_mfma_f32_32x32x16_bf16(BUF[j], whf[BASE + j], acc,  \
                                                    0, 0, 0);

__global__ __launch_bounds__(256, 1) void k_scan(
    const unsigned short* __restrict__ xf,
    const unsigned short* __restrict__ wp,
    const float* __restrict__ bias,
    float* __restrict__ out,
    unsigned* __restrict__ hdr,
    unsigned* __restrict__ done,
    unsigned short* __restrict__ hring) {
  __shared__ __align__(16) unsigned short Wlds[4][32][64][8];  // 131072 B exactly

  const int tid = threadIdx.x;
  const int lane = tid & 63;
  const int w = tid >> 6;
  const int bid = blockIdx.x;
  const int rg = bid & 7;
  const int cm = bid >> 3;

  // one-time: Wx frags -> LDS (all 4 waves' tiles)
  for (int i = tid; i < 4 * 32 * 64; i += 256) {
    int ww = i >> 11, r = i & 2047, kx = r >> 6, l = r & 63;
    *(short8*)&Wlds[ww][kx][l][0] =
        *(const short8*)(wp + (((size_t)(cm * 4 + ww) * 96 + kx) * 64 + l) * 8);
  }
  // one-time: Wh frags -> 256 VGPRs (64 K-steps x 16 cols each)
  short8 whf[64];
#pragma unroll
  for (int kh = 0; kh < 64; ++kh)
    whf[kh] = *(const short8*)(
        wp + (((size_t)(cm * 4 + w) * 96 + 32 + kh) * 64 + lane) * 8);

  // ---- XCD consensus (global-only, no LDS): group on a single XCD? ----
  if (tid == 0) {
    unsigned xcc = 0;
    asm volatile("s_getreg_b32 %0, hwreg(HW_REG_XCC_ID)" : "=s"(xcc));
    __hip_atomic_fetch_or(hdr + rg, 1u << (xcc & 31u), __ATOMIC_RELAXED,
                          __HIP_MEMORY_SCOPE_AGENT);
    __hip_atomic_fetch_add(hdr + 16, 1u, __ATOMIC_RELEASE, __HIP_MEMORY_SCOPE_AGENT);
  }
  while (__hip_atomic_load(hdr + 16, __ATOMIC_ACQUIRE, __HIP_MEMORY_SCOPE_AGENT) <
         256u)
    __builtin_amdgcn_s_sleep(8);
  const bool fastc =
      (__popc(__hip_atomic_load(hdr + rg, __ATOMIC_RELAXED,
                                __HIP_MEMORY_SCOPE_AGENT)) == 1);

  // ---- fast-path self-test: prove L2-scope atomics rendezvous in the group ----
  if (fastc && lane == 0)
    __hip_atomic_fetch_add(hdr + 32 + rg, 1u, __ATOMIC_RELAXED,
                           __HIP_MEMORY_SCOPE_WORKGROUP);
  __syncthreads();   // also orders Wlds writes vs X-phase reads
  if (tid == 0) {
    int ok = 1;
    if (fastc) {
      unsigned v = 0;
      int it = 0;
      do {
        asm volatile("global_load_dword %0, %1, off sc0\n\ts_waitcnt vmcnt(0)"
                     : "=v"(v) : "v"(hdr + 32 + rg) : "memory");
        if (v == 128u) break;
        __builtin_amdgcn_s_sleep(8);
      } while (++it < 30000);
      ok = (v == 128u) ? 1 : 0;
    }
    if (!ok)
      __hip_atomic_fetch_or(hdr + 48 + rg, 1u, __ATOMIC_RELAXED,
                            __HIP_MEMORY_SCOPE_AGENT);
    __hip_atomic_fetch_add(hdr + 17, 1u, __ATOMIC_RELEASE, __HIP_MEMORY_SCOPE_AGENT);
  }
  while (__hip_atomic_load(hdr + 17, __ATOMIC_ACQUIRE, __HIP_MEMORY_SCOPE_AGENT) <
         256u)
    __builtin_amdgcn_s_sleep(8);
  const bool fastp =
      fastc && (__hip_atomic_load(hdr + 48 + rg, __ATOMIC_RELAXED,
                                  __HIP_MEMORY_SCOPE_AGENT) == 0u);
  __syncthreads();

  // per-lane roles
  const int m = lane & 7;              // batch row within group
  const int uu = lane >> 3;            // unit within wave's 8
  const int ug = cm * 32 + w * 8 + uu; // global unit
  const float bi = bias[ug], bf_ = bias[1024 + ug];
  const float bc_ = bias[2048 + ug], bo = bias[3072 + ug];
  const int r3 = m & 3;
  const int sbase = ((m >> 2) & 1) * 32 + uu;  // gather source lane base
  float c_state = 0.f;

  const unsigned short* xl = xf + (lane & 7) * 16 + (lane >> 5) * 8;
  const unsigned short* wxl = (const unsigned short*)&Wlds[w][0][lane][0];
  const int hcell = cm * 2 + (w >> 1);

#pragma unroll 1
  for (int t = 0; t < T_STEPS; ++t) {
    f32x16 acc;
#pragma unroll
    for (int r = 0; r < 16; ++r) acc[r] = 0.f;

    // ---- X phase: A from xf cells (plain), B from LDS; overlaps group slack ----
    {
      const unsigned short* xs = xl + (size_t)(rg * 512 + t) * 4096;
#pragma unroll 8
      for (int kx = 0; kx < 32; ++kx) {
        short8 xa = *(const short8*)(xs + kx * 128);
        short8 wb = *(const short8*)(wxl + kx * 512);
        acc = __builtin_amdgcn_mfma_f32_32x32x16_bf16(xa, wb, acc, 0, 0, 0);
      }
    }
    asm volatile("s_waitcnt vmcnt(0)" ::: "memory");  // clean vmcnt baseline

    // ---- wake: all lanes load the 8 group counters of t-1 (one instr/poll) ----
    if (t > 0) {
      const unsigned* dp =
          done + ((size_t)(rg * 512 + (t - 1)) * 8 + (lane & 7)) * 16;
      unsigned v;
      if (fastp) {
        for (;;) {
          asm volatile("global_load_dword %0, %1, off sc0\n\ts_waitcnt vmcnt(0)"
                       : "=v"(v) : "v"(dp) : "memory");
          if (__all(v == 16u)) break;
          __builtin_amdgcn_s_sleep(1);
        }
      } else {
        for (;;) {
          v = __hip_atomic_load(dp, __ATOMIC_RELAXED, __HIP_MEMORY_SCOPE_AGENT);
          if (__all(v == 16u)) break;
          __builtin_amdgcn_s_sleep(2);
        }
      }
    }
    __builtin_amdgcn_sched_barrier(0);

    // ---- H phase: 64 K-steps (K=1024), A from ring (L2/LLC), B from VGPRs ----
    // 8-batch ping-pong, 16 loads outstanding max; vmcnt(8) frees oldest batch.
    {
      const unsigned short* hb = hring + (size_t)(t & (RING - 1)) * 65536 +
                                 rg * 8192 + (lane & 7) * 16 + (lane >> 5) * 8;
      short8 hA[8], hB[8];
      if (fastp) {
        H_LDF(hA, 0)  H_LDF(hB, 8)
        H_WAIT8 H_MM(hA, 0)
        H_LDF(hA, 16) H_WAIT8 H_MM(hB, 8)
        H_LDF(hB, 24) H_WAIT8 H_MM(hA, 16)
        H_LDF(hA, 32) H_WAIT8 H_MM(hB, 24)
        H_LDF(hB, 40) H_WAIT8 H_MM(hA, 32)
        H_LDF(hA, 48) H_WAIT8 H_MM(hB, 40)
        H_LDF(hB, 56) H_WAIT8 H_MM(hA, 48)
        H_WAIT0 H_MM(hB, 56)
      } else {
        H_LDA(hA, 0)  H_LDA(hB, 8)
        H_WAIT8 H_MM(hA, 0)
        H_LDA(hA, 16) H_WAIT8 H_MM(hB, 8)
        H_LDA(hB, 24) H_WAIT8 H_MM(hA, 16)
        H_LDA(hA, 32) H_WAIT8 H_MM(hB, 24)
        H_LDA(hB, 40) H_WAIT8 H_MM(hA, 32)
        H_LDA(hA, 48) H_WAIT8 H_MM(hB, 40)
        H_LDA(hB, 56) H_WAIT8 H_MM(hA, 48)
        H_WAIT0 H_MM(hB, 56)
      }
    }

    // ---- gather 4 gates via shuffles (C: col=lane&31, row=(r&3)+8(r>>2)+4hh) ----
    float sg0, sg1, sg2, sg3;
    {
      float v0, v1, v2, v3;
      v0 = __shfl(acc[0], sbase + 0, 64);  v1 = __shfl(acc[1], sbase + 0, 64);
      v2 = __shfl(acc[2], sbase + 0, 64);  v3 = __shfl(acc[3], sbase + 0, 64);
      sg0 = r3 == 0 ? v0 : r3 == 1 ? v1 : r3 == 2 ? v2 : v3;
      v0 = __shfl(acc[0], sbase + 8, 64);  v1 = __shfl(acc[1], sbase + 8, 64);
      v2 = __shfl(acc[2], sbase + 8, 64);  v3 = __shfl(acc[3], sbase + 8, 64);
      sg1 = r3 == 0 ? v0 : r3 == 1 ? v1 : r3 == 2 ? v2 : v3;
      v0 = __shfl(acc[0], sbase + 16, 64); v1 = __shfl(acc[1], sbase + 16, 64);
      v2 = __shfl(acc[2], sbase + 16, 64); v3 = __shfl(acc[3], sbase + 16, 64);
      sg2 = r3 == 0 ? v0 : r3 == 1 ? v1 : r3 == 2 ? v2 : v3;
      v0 = __shfl(acc[0], sbase + 24, 64); v1 = __shfl(acc[1], sbase + 24, 64);
      v2 = __shfl(acc[2], sbase + 24, 64); v3 = __shfl(acc[3], sbase + 24, 64);
      sg3 = r3 == 0 ? v0 : r3 == 1 ? v1 : r3 == 2 ? v2 : v3;
    }

    // ---- gate math (fast tanh via __expf) ----
    float sI = sg0 + bi, sF = sg1 + bf_, sC = sg2 + bc_, sO = sg3 + bo;
    float ig = 1.f / (1.f + __expf(-sI));
    float fg = 1.f / (1.f + __expf(-sF));
    float og = 1.f / (1.f + __expf(-sO));
    float aC = fabsf(sC), eC = __expf(-2.f * aC);
    float tC = __builtin_copysignf((1.f - eC) / (1.f + eC), sC);
    c_state = fg * c_state + ig * tC;
    float aH = fabsf(c_state), eH = __expf(-2.f * aH);
    float th = __builtin_copysignf((1.f - eH) / (1.f + eH), c_state);
    float h = og * th;

    // ---- pack 8 units/row via xor-8/16/32 butterflies, 16B store by lanes 0..7 ----
    unsigned hv = (unsigned)f2bf(h);
    unsigned p1 = (unsigned)__shfl_xor((int)hv, 8, 64);
    unsigned lo = hv | (p1 << 16);
    unsigned p2 = (unsigned)__shfl_xor((int)lo, 16, 64);
    unsigned p3a = (unsigned)__shfl_xor((int)lo, 32, 64);
    unsigned p3b = (unsigned)__shfl_xor((int)p2, 32, 64);
    if (lane < 8) {
      unsigned short* hd = hring + (size_t)((t + 1) & (RING - 1)) * 65536 +
                           rg * 8192 + hcell * 128 + lane * 16 + (w & 1) * 8;
      if (fastp) {
        union { unsigned u[4]; short8 s; } pk;
        pk.u[0] = lo; pk.u[1] = p2; pk.u[2] = p3a; pk.u[3] = p3b;
        *(short8*)hd = pk.s;
      } else {
        unsigned long long a = ((unsigned long long)p2 << 32) | lo;
        unsigned long long b2 = ((unsigned long long)p3b << 32) | p3a;
        __hip_atomic_store((unsigned long long*)hd, a, __ATOMIC_RELAXED,
                           __HIP_MEMORY_SCOPE_AGENT);
        __hip_atomic_store(((unsigned long long*)hd) + 1, b2, __ATOMIC_RELAXED,
                           __HIP_MEMORY_SCOPE_AGENT);
      }
    }
    if (t == T_STEPS - 1) {
      float* orow = out + (size_t)(rg * 8 + m) * 3072 + ug;
      orow[0] = h;
      orow[1024] = h;
      orow[2048] = c_state;
    }

    // ---- drain stores, then per-wave flag (no block barrier) ----
    asm volatile("s_waitcnt vmcnt(0)" ::: "memory");
    if (lane == 0) {
      unsigned* dadd = done + ((size_t)(rg * 512 + t) * 8 + (cm >> 2)) * 16;
      if (fastp)
        __hip_atomic_fetch_add(dadd, 1u, __ATOMIC_RELAXED,
                               __HIP_MEMORY_SCOPE_WORKGROUP);
      else
        __hip_atomic_fetch_add(dadd, 1u, __ATOMIC_RELAXED,
                               __HIP_MEMORY_SCOPE_AGENT);
    }
    __builtin_amdgcn_sched_barrier(0);
  }
}

extern "C" void kernel_launch(void* const* d_in, const int* in_sizes, int n_in,
                              void* d_out, int out_size, void* d_ws, size_t ws_size,
                              hipStream_t stream) {
  (void)in_sizes; (void)n_in; (void)out_size; (void)ws_size;
  const float* x = (const float*)d_in[0];
  const float* Wx = (const float*)d_in[1];
  const float* Wh = (const float*)d_in[2];
  const float* b = (const float*)d_in[3];
  float* out = (float*)d_out;
  char* ws = (char*)d_ws;
  unsigned* hdr = (unsigned*)(ws + OFF_HDR);
  unsigned* done = (unsigned*)(ws + OFF_DONE);
  unsigned short* hring = (unsigned short*)(ws + OFF_RING);
  unsigned short* xf = (unsigned short*)(ws + OFF_XF);
  unsigned short* wp = (unsigned short*)(ws + OFF_WP);

  hipMemsetAsync(d_ws, 0, MEMSET_BYTES, stream);
  k_xpack<<<8192, 256, 0, stream>>>(x, xf);
  k_wpack<<<dim3(12, 128), 256, 0, stream>>>(Wx, Wh, wp);

  void* args[] = {(void*)&xf, (void*)&wp, (void*)&b, (void*)&out,
                  (void*)&hdr, (void*)&done, (void*)&hring};
  hipError_t e = hipLaunchCooperativeKernel((void*)k_scan, dim3(256), dim3(256),
                                            args, 0, stream);
  if (e != hipSuccess) {
    // 256 blocks x 128 KiB LDS -> 1 block/CU on 256 CUs: all co-resident,
    // flag protocol (no grid.sync) remains valid under a plain launch.
    k_scan<<<dim3(256), dim3(256), 0, stream>>>(xf, wp, b, out, hdr, done, hring);
  }
}

// Round 4
// 2984.336 us; speedup vs baseline: 1.9320x; 1.9320x over previous
//
#include <hip/hip_runtime.h>
#include <stdint.h>

#define T_STEPS 512
#define RING 16
#define SLOT_SHORTS 65536   // one h slot: [2 g][4 ks][16 kk][64 lane][8] bf16 = 128 KB

typedef short short8 __attribute__((ext_vector_type(8)));
typedef float f32x16 __attribute__((ext_vector_type(16)));

// ---- ws layout (bytes) ----
// ep region: [2 g][128 cb] monotonic epoch words, 16B stride (4 KB used of 256 KB)
#define OFF_EP 0
#define EP_BYTES (512 * 2 * 4 * 64)                 // 256 KB (legacy size, reused)
#define OFF_HRING EP_BYTES                          // 16 slots x 128 KB = 2 MB
#define OFF_XF (OFF_HRING + RING * SLOT_SHORTS * 2) // x in A-frag order, 32 MB
#define XF_BYTES (512 * 2 * 4 * 8 * 64 * 8 * 2)
#define OFF_WPACK (OFF_XF + XF_BYTES)               // [4096][1536] bf16 = 12 MB
#define MEMSET_BYTES (OFF_HRING + SLOT_SHORTS * 2)  // epochs + ring slot 0 (h_{-1}=0)

// LDS strides
#define W_STR 1544   // shorts = 772 dw
#define G_STR 36     // floats

__device__ __forceinline__ unsigned short f2bf(float f) {
  unsigned u = __float_as_uint(f);
  u += 0x7fffu + ((u >> 16) & 1u);   // RNE
  return (unsigned short)(u >> 16);
}

// ---- prep: x [B][T][D] f32 -> xf [t][g][ks][kk][lane=hh*32+n][8] bf16 ----
__global__ __launch_bounds__(256) void k_xpack(const float* __restrict__ x,
                                               unsigned short* __restrict__ xf) {
  int o = blockIdx.x * 256 + threadIdx.x;   // 2,097,152 vec8 cells
  int lane = o & 63;
  int kk = (o >> 6) & 7;
  int ks = (o >> 9) & 3;
  int g = (o >> 11) & 1;
  int t = o >> 12;
  int n = lane & 31, hh = lane >> 5;
  const float* src = x + (((size_t)(g * 32 + n) * 512 + t) * 512 +
                          ks * 128 + kk * 16 + hh * 8);
  float4 v0 = *(const float4*)src;
  float4 v1 = *(const float4*)(src + 4);
  short8 w;
  w[0] = (short)f2bf(v0.x); w[1] = (short)f2bf(v0.y);
  w[2] = (short)f2bf(v0.z); w[3] = (short)f2bf(v0.w);
  w[4] = (short)f2bf(v1.x); w[5] = (short)f2bf(v1.y);
  w[6] = (short)f2bf(v1.z); w[7] = (short)f2bf(v1.w);
  *(short8*)(xf + (size_t)o * 8) = w;
}

// ---- prep: W [k][col] f32 -> wp [colpack][k] bf16 ----
// col = g*1024 + u  ->  cp = (u>>3)*32 + g*8 + (u&7)
__global__ __launch_bounds__(256) void k_wpack(const float* __restrict__ Wx,
                                               const float* __restrict__ Wh,
                                               unsigned short* __restrict__ wp) {
  __shared__ unsigned short tile[64 * 68];
  int tid = threadIdx.x, lane = tid & 63, wave = tid >> 6;
  int kt = blockIdx.x >> 6;   // 0..23
  int ct = blockIdx.x & 63;   // 0..63
  int K0 = kt * 64, C0 = ct * 64;
  const float* src = (K0 < 512) ? (Wx + (size_t)K0 * 4096)
                                : (Wh + (size_t)(K0 - 512) * 4096);
  #pragma unroll
  for (int i = 0; i < 16; ++i) {
    int kl = i * 4 + wave;
    float v = src[(size_t)kl * 4096 + C0 + lane];
    tile[lane * 68 + kl] = f2bf(v);
  }
  __syncthreads();
  #pragma unroll
  for (int i = 0; i < 16; ++i) {
    int c = i * 4 + wave;
    int col = C0 + c;
    int gg = col >> 10, idx = col & 1023;
    int cp = (idx >> 3) * 32 + gg * 8 + (idx & 7);
    wp[(size_t)cp * 1536 + K0 + lane] = tile[c * 68 + lane];
  }
}

// ---- persistent scan (R0 structure + shortened rendezvous chain) ----
// 256 blocks x 256 threads. g = bid&1 (32 batch rows), cb = bid>>1 (8 units).
// Wave = K-slice ks. All global A-stream loads 16B/lane coalesced (R9).
// R4 deltas vs R0 (proven 2290us):
//  D1: X_{t+1} issued between h-store and drain -> store-ACK off critical chain.
//  D2: per-block monotonic epoch word (plain agent store) replaces the shared
//      atomicAdd counters -> removes LLC RMW serialization from the chain.
//      Wave ks polls the 32 producer epochs of its own K-slice (one lane-par load).
//  D3: s_sleep(1) poll backoff instead of burn-FMA.
__global__ __launch_bounds__(256, 1) void k_scan(
    const unsigned short* __restrict__ xf,
    const unsigned short* __restrict__ wp,
    const float* __restrict__ bias,
    float* __restrict__ out,
    unsigned* __restrict__ ep,
    unsigned short* __restrict__ hring) {
  __shared__ __align__(16) unsigned short Wlds[32 * W_STR];   // 98816 B
  __shared__ float Gs[4][32 * G_STR];                         // 18432 B

  const int tid = threadIdx.x;
  const int lane = tid & 63;
  const int ks = tid >> 6;          // wave = K-slice
  const int bid = blockIdx.x;
  const int g = bid & 1;            // batch group (rows g*32..g*32+31)
  const int cb = bid >> 1;          // col-block (units cb*8..cb*8+7)
  const int n = lane & 31;          // MFMA row/col index within tile
  const int hh = lane >> 5;         // k-half selector

  // one-time: weights -> LDS (32 local cols x 1536 K)
  for (int i = tid; i < 32 * 192; i += 256) {
    int row = i / 192, o = i % 192;
    *(short8*)&Wlds[row * W_STR + o * 8] =
        *(const short8*)&wp[((size_t)cb * 32 + row) * 1536 + o * 8];
  }

  const int m = tid >> 3, uu = tid & 7;   // gate-math thread = (batch row m, unit uu)
  const int ug = cb * 8 + uu;
  const float bi = bias[ug], bff = bias[1024 + ug];
  const float bc_ = bias[2048 + ug], bo = bias[3072 + ug];
  float c_state = 0.f;
  // producer fragment cell for this block's 8 units:
  const int ksp = cb >> 5, kkp = (cb >> 1) & 15, hhp = cb & 1;
  __syncthreads();

  const unsigned short* wb = &Wlds[n * W_STR + hh * 8];

  // ---- prologue: X contribution for t=0 ----
  f32x16 acc;
  #pragma unroll
  for (int r = 0; r < 16; ++r) acc[r] = 0.f;
  {
    const unsigned short* xs = xf + ((size_t)(g * 4 + ks) * 8) * 512 + lane * 8;
    #pragma unroll
    for (int kk = 0; kk < 8; ++kk) {
      short8 xa = *(const short8*)(xs + kk * 512);
      short8 b = *(const short8*)(wb + ks * 128 + kk * 16);
      acc = __builtin_amdgcn_mfma_f32_32x32x16_bf16(xa, b, acc, 0, 0, 0);
    }
  }

  #pragma unroll 1
  for (int t = 0; t < T_STEPS; ++t) {
    // ---- wake: poll the 32 producer epochs of this wave's K-slice ----
    if (t > 0) {
      const unsigned* dp = ep + ((size_t)g * 128 + ks * 32 + (lane & 31)) * 4;
      for (;;) {
        unsigned v = __hip_atomic_load(dp, __ATOMIC_RELAXED,
                                       __HIP_MEMORY_SCOPE_AGENT);
        if (__all((int)(v >= (unsigned)t))) break;
        __builtin_amdgcn_s_sleep(1);
      }
    }
    // compiler ordering guard: h loads below must not hoist above the spin
    __builtin_amdgcn_fence(__ATOMIC_ACQUIRE, "workgroup");
    // windowed invalidate: ring lines recycle every 16 steps
    if (t > 0 && (t & (RING - 1)) == 0)
      __builtin_amdgcn_fence(__ATOMIC_ACQUIRE, "agent");

    // ---- H phase: coalesced fragment loads (16B/lane), MFMA vs LDS weights ----
    {
      const unsigned short* hs = hring + (size_t)(t & (RING - 1)) * SLOT_SHORTS +
                                 ((g * 4 + ks) * 16) * 512 + lane * 8;
      short8 ha[16];
      #pragma unroll
      for (int kk = 0; kk < 16; ++kk)
        ha[kk] = *(const short8*)(hs + kk * 512);
      #pragma unroll
      for (int kk = 0; kk < 16; ++kk) {
        short8 b = *(const short8*)(wb + 512 + ks * 256 + kk * 16);
        acc = __builtin_amdgcn_mfma_f32_32x32x16_bf16(ha[kk], b, acc, 0, 0, 0);
      }
    }

    // ---- partials to LDS (32x32 C/D: col=lane&31, row=(r&3)+8*(r>>2)+4*(lane>>5)) ----
    #pragma unroll
    for (int r = 0; r < 16; ++r) {
      int row = (r & 3) + 8 * (r >> 2) + 4 * hh;
      Gs[ks][row * G_STR + n] = acc[r];
    }
    __syncthreads();

    // ---- gate math: all 256 threads, (m, uu); sum 4 K-slice partials ----
    float sI = bi, sF = bff, sC = bc_, sO = bo;
    #pragma unroll
    for (int w = 0; w < 4; ++w) {
      sI += Gs[w][m * G_STR + uu];
      sF += Gs[w][m * G_STR + 8 + uu];
      sC += Gs[w][m * G_STR + 16 + uu];
      sO += Gs[w][m * G_STR + 24 + uu];
    }
    float ig = 1.f / (1.f + __expf(-sI));
    float fg = 1.f / (1.f + __expf(-sF));
    float og = 1.f / (1.f + __expf(-sO));
    float cb2 = tanhf(sC);
    c_state = fg * c_state + ig * cb2;
    float h = og * tanhf(c_state);

    // pack 4 units -> 8B agent-scope store into the NEXT slot's fragment cell
    unsigned hv = (unsigned)f2bf(h);
    unsigned o1 = (unsigned)__shfl_xor((int)hv, 1, 64);
    unsigned lo = hv | (o1 << 16);
    unsigned long long hi = (unsigned long long)(unsigned)__shfl_xor((int)lo, 2, 64);
    unsigned long long v64 = ((unsigned long long)lo) | (hi << 32);
    if ((uu & 3) == 0) {
      unsigned short* hdst = hring + (size_t)((t + 1) & (RING - 1)) * SLOT_SHORTS +
                             ((g * 4 + ksp) * 16 + kkp) * 512 +
                             (hhp * 32 + m) * 8 + uu;
      __hip_atomic_store((unsigned long long*)hdst, v64,
                         __ATOMIC_RELAXED, __HIP_MEMORY_SCOPE_AGENT);
    }
    if (t == T_STEPS - 1) {
      float* orow = out + (size_t)(g * 32 + m) * 3072 + ug;
      orow[0] = h;
      orow[1024] = h;
      orow[2048] = c_state;
    }

    // ---- X phase for t+1: overlaps the h-store's LLC write-through ACK ----
    f32x16 acc2;
    #pragma unroll
    for (int r = 0; r < 16; ++r) acc2[r] = 0.f;
    {
      int tx = (t + 1) & (T_STEPS - 1);   // t=511 -> dummy re-read of t=0 (valid)
      const unsigned short* xs =
          xf + ((((size_t)tx * 2 + g) * 4 + ks) * 8) * 512 + lane * 8;
      #pragma unroll
      for (int kk = 0; kk < 8; ++kk) {
        short8 xa = *(const short8*)(xs + kk * 512);
        short8 b = *(const short8*)(wb + ks * 128 + kk * 16);
        acc2 = __builtin_amdgcn_mfma_f32_32x32x16_bf16(xa, b, acc2, 0, 0, 0);
      }
    }
    asm volatile("s_waitcnt vmcnt(0)" ::: "memory");  // h stores ACKed at LLC
    __syncthreads();   // all 4 waves' cell stores drained
    if (tid == 0)
      __hip_atomic_store(ep + ((size_t)g * 128 + cb) * 4, (unsigned)(t + 1),
                         __ATOMIC_RELAXED, __HIP_MEMORY_SCOPE_AGENT);
    acc = acc2;
  }
}

extern "C" void kernel_launch(void* const* d_in, const int* in_sizes, int n_in,
                              void* d_out, int out_size, void* d_ws, size_t ws_size,
                              hipStream_t stream) {
  (void)in_sizes; (void)n_in; (void)out_size; (void)ws_size;
  const float* x  = (const float*)d_in[0];
  const float* Wx = (const float*)d_in[1];
  const float* Wh = (const float*)d_in[2];
  const float* b  = (const float*)d_in[3];
  float* out = (float*)d_out;
  char* ws = (char*)d_ws;
  unsigned* ep = (unsigned*)(ws + OFF_EP);
  unsigned short* hring = (unsigned short*)(ws + OFF_HRING);
  unsigned short* xf = (unsigned short*)(ws + OFF_XF);
  unsigned short* wp = (unsigned short*)(ws + OFF_WPACK);

  hipMemsetAsync(d_ws, 0, MEMSET_BYTES, stream);
  k_xpack<<<8192, 256, 0, stream>>>(x, xf);
  k_wpack<<<1536, 256, 0, stream>>>(Wx, Wh, wp);

  void* args[] = {(void*)&xf, (void*)&wp, (void*)&b, (void*)&out, (void*)&ep,
                  (void*)&hring};
  hipError_t e = hipLaunchCooperativeKernel((void*)k_scan, dim3(256), dim3(256),
                                            args, 0, stream);
  if (e != hipSuccess) {
    // 256 blocks, 117 KB LDS -> 1 block/CU on 256 CUs: all co-resident; the
    // flag protocol (no grid.sync) remains valid under a plain launch.
    k_scan<<<dim3(256), dim3(256), 0, stream>>>(xf, wp, b, out, ep, hring);
  }
}